// Round 7
// baseline (291.553 us; speedup 1.0000x reference)
//
#include <hip/hip_runtime.h>
#include <math.h>

#define LMAX  32768
#define WWIN  1024
#define KFIR  128
#define WOUT  256                // outputs per wave (4 per lane, consecutive)
#define TO    1024               // outputs per block (4 waves)
#define HALO  128
#define SEGW  384                // 256 + 128 staged samples per wave
#define NMAX  1024               // max notes

// ---------------- per-note parameter kernel ----------------
__global__ __launch_bounds__(256) void params_k(
    const float* __restrict__ freq, const float* __restrict__ velo,
    const float* __restrict__ w1,  const float* __restrict__ b1,
    const float* __restrict__ w2,  const float* __restrict__ b2,
    const float* __restrict__ ws1, const float* __restrict__ bs1,
    const float* __restrict__ ws2, const float* __restrict__ bs2,
    const int* __restrict__ starts, const int* __restrict__ lengths,
    int Dn, int N,
    float* __restrict__ amps_out, int* __restrict__ outlen_out,
    float* __restrict__ veln_out)
{
    __shared__ float s_w1[32], s_b1[32], s_w2[64], s_b2[2];
    __shared__ float s_ws1[256], s_bs1[64], s_ws2[512], s_bs2[8];

    const int tid = threadIdx.x;
    if (tid < 32)  { s_w1[tid] = w1[tid]; s_b1[tid] = b1[tid]; }
    if (tid < 64)  { s_w2[tid] = w2[tid]; s_bs1[tid] = bs1[tid]; }
    if (tid < 2)   s_b2[tid] = b2[tid];
    if (tid < 8)   s_bs2[tid] = bs2[tid];
    s_ws1[tid] = ws1[tid];
    s_ws2[tid] = ws2[tid];
    s_ws2[tid + 256] = ws2[tid + 256];
    __syncthreads();

    const int n = blockIdx.x * blockDim.x + tid;
    if (n >= N) return;

    int st  = starts[n];
    int len = lengths[n];
    int ol  = min(st + len, Dn) - st;
    ol = max(0, min(ol, LMAX));
    outlen_out[n] = ol;

    float v = velo[n] * (1.0f / 127.0f);
    veln_out[n] = v;

    float nt = (float)st / (float)Dn;

    float lat0 = s_b2[0], lat1 = s_b2[1];
    #pragma unroll
    for (int j = 0; j < 32; ++j) {
        float h = fmaxf(fmaf(nt, s_w1[j], s_b1[j]), 0.0f);
        lat0 = fmaf(h, s_w2[j * 2 + 0], lat0);
        lat1 = fmaf(h, s_w2[j * 2 + 1], lat1);
    }

    const float f0 = freq[n], f1 = v, f2 = lat0, f3 = lat1;

    float acc[8];
    #pragma unroll
    for (int h = 0; h < 8; ++h) acc[h] = s_bs2[h];
    #pragma unroll
    for (int j = 0; j < 64; ++j) {
        float a = s_bs1[j];
        a = fmaf(f0, s_ws1[0 * 64 + j], a);
        a = fmaf(f1, s_ws1[1 * 64 + j], a);
        a = fmaf(f2, s_ws1[2 * 64 + j], a);
        a = fmaf(f3, s_ws1[3 * 64 + j], a);
        a = fmaxf(a, 0.0f);
        #pragma unroll
        for (int h = 0; h < 8; ++h)
            acc[h] = fmaf(a, s_ws2[j * 8 + h], acc[h]);
    }
    #pragma unroll
    for (int h = 0; h < 8; ++h) {
        float a = acc[h];
        float sp = fmaxf(a, 0.0f) + log1pf(expf(-fabsf(a)));
        amps_out[n * 8 + h] = sp;
    }
}

__device__ __forceinline__ float fast_tanh(float x) {
    float e = __builtin_amdgcn_exp2f(x * 2.8853900817779268f);  // 2*log2(e)
    return fmaf(-2.0f, __builtin_amdgcn_rcpf(e + 1.0f), 1.0f);
}

// ---------------- gather synthesis kernel ----------------
// grid: ceil(Dn/TO) blocks, 256 threads = 4 independent waves.
// Each wave owns WOUT=256 consecutive outputs (4/lane) + a private LDS slice.
// Note list built once per block; no barriers in the pair loop.
// Next-pair note parameters are prefetched (software pipeline) to hide s_load latency.
__global__ __launch_bounds__(256, 4) void synth_gather_k(
    const float* __restrict__ freq_g, const int* __restrict__ starts,
    const float* __restrict__ amps_g, const int* __restrict__ outlen_g,
    const float* __restrict__ veln_g, const float* __restrict__ fir,
    float* __restrict__ out, int Dn, int N)
{
    __shared__ __align__(16) float seg[4][SEGW];
    __shared__ __align__(16) float fir_s[KFIR];
    __shared__ unsigned short note_list[NMAX];
    __shared__ int note_cnt;

    const int tid  = threadIdx.x;
    const int wid  = tid >> 6;
    const int lane = tid & 63;
    const int o0   = blockIdx.x * TO;
    const int o_end = min(o0 + TO, Dn);
    const int ow   = o0 + wid * WOUT;         // this wave's first output

    if (tid < KFIR) fir_s[tid] = fir[tid];
    if (tid == 0) note_cnt = 0;
    __syncthreads();
    for (int j = tid; j < N; j += 256) {
        int st = starts[j];
        int ol = outlen_g[j];
        if (st < o_end && st + ol > o0) {
            int p = atomicAdd(&note_cnt, 1);
            note_list[p] = (unsigned short)j;
        }
    }
    __syncthreads();
    const int K = note_cnt;

    float* __restrict__ segw = seg[wid];
    const int a = lane * 4;                   // wave-local output index / LDS dword base
    float acc0 = 0.f, acc1 = 0.f, acc2 = 0.f, acc3 = 0.f;

    const double inv2pi = 0.15915494309189535;
    const float4* __restrict__ amps4 = (const float4*)amps_g;

    // ---- prefetch pair 0's parameters ----
    int stN = 0, olN = 0; float fN = 0.f, vN = 0.f;
    float4 amN0 = {}, amN1 = {};
    if (K > 0) {
        const int nid = __builtin_amdgcn_readfirstlane((int)note_list[0]);
        stN = starts[nid]; olN = outlen_g[nid];
        fN = freq_g[nid];  vN = veln_g[nid];
        amN0 = amps4[nid * 2]; amN1 = amps4[nid * 2 + 1];
    }

    for (int kk = 0; kk < K; ++kk) {
        // consume prefetched params
        const int st = stN, ol = olN;
        const float f = fN, v = vN;
        const float4 am0 = amN0, am1 = amN1;
        // issue next pair's loads (independent of this pair's compute)
        if (kk + 1 < K) {
            const int nid = __builtin_amdgcn_readfirstlane((int)note_list[kk + 1]);
            stN = starts[nid]; olN = outlen_g[nid];
            fN = freq_g[nid];  vN = veln_g[nid];
            amN0 = amps4[nid * 2]; amN1 = amps4[nid * 2 + 1];
        }

        const int base = ow - st;             // note-local index of wave's first output
        if (base >= ol || base + WOUT <= 0) continue;   // wave-uniform skip

        const float A0 = am0.x, A1 = am0.y, A2 = am0.z, A3 = am0.w;
        const float A4 = am1.x, A5 = am1.y, A6 = am1.z, A7 = am1.w;
        const double fd = (double)f;

        // phase seed (f64 once per pair) + fixed-angle rotation stepping (64 samples)
        const int tseed = base - HALO + lane;
        double rev0 = fd * (double)tseed * inv2pi;
        float r0 = (float)(rev0 - floor(rev0));
        float s = __builtin_amdgcn_sinf(r0);
        float c = __builtin_amdgcn_cosf(r0);
        double d64 = fd * 64.0 * inv2pi;
        float r64 = (float)(d64 - floor(d64));
        const float sd = __builtin_amdgcn_sinf(r64);
        const float cd = __builtin_amdgcn_cosf(r64);
        const int wbase = ol - WWIN;

        // ---- stage SEGW samples (same-wave write->read, no barrier) ----
        #pragma unroll
        for (int i = 0; i < 6; ++i) {
            int t = tseed + 64 * i;
            float val = 0.0f;
            if (t >= 0 && t < ol) {
                float tc = c + c;
                float sA = s;
                float sum = A0 * sA;
                float sB = tc * sA;              sum = fmaf(A1, sB, sum);
                float sC = fmaf(tc, sB, -sA);    sum = fmaf(A2, sC, sum);
                float sD = fmaf(tc, sC, -sB);    sum = fmaf(A3, sD, sum);
                float sE = fmaf(tc, sD, -sC);    sum = fmaf(A4, sE, sum);
                float sF = fmaf(tc, sE, -sD);    sum = fmaf(A5, sF, sum);
                float sG = fmaf(tc, sF, -sE);    sum = fmaf(A6, sG, sum);
                float sH = fmaf(tc, sG, -sF);    sum = fmaf(A7, sH, sum);
                int wpos = t - wbase;
                float factor = 1.0f;
                if (wpos >= 0)
                    factor = 0.5f - 0.5f * __builtin_amdgcn_cosf((float)wpos * (1.0f / WWIN));
                val = v * sum * factor;
            }
            segw[lane + 64 * i] = val;
            float ns = fmaf(s, cd, c * sd);
            float nc = fmaf(c, cd, -(s * sd));
            s = ns; c = nc;
        }

        // ---- 128-tap FIR, 4 outputs/lane, sliding register window ----
        // (plain layout: base + immediate offsets -> no addr registers, no spill)
        float w1r, w2r, w3r;
        {
            float4 cur = *(const float4*)&segw[a];
            w1r = cur.y; w2r = cur.z; w3r = cur.w;
        }
        float y0 = 0.f, y1 = 0.f, y2 = 0.f, y3 = 0.f;
        #pragma unroll
        for (int m = 0; m < 32; ++m) {
            float4 tv  = *(const float4*)&fir_s[4 * m];       // uniform broadcast
            float4 nxt = *(const float4*)&segw[a + 4 * m + 4];
            float w4r = nxt.x, w5r = nxt.y, w6r = nxt.z, w7r = nxt.w;
            y0 = fmaf(tv.x, w1r, y0); y1 = fmaf(tv.x, w2r, y1);
            y2 = fmaf(tv.x, w3r, y2); y3 = fmaf(tv.x, w4r, y3);
            y0 = fmaf(tv.y, w2r, y0); y1 = fmaf(tv.y, w3r, y1);
            y2 = fmaf(tv.y, w4r, y2); y3 = fmaf(tv.y, w5r, y3);
            y0 = fmaf(tv.z, w3r, y0); y1 = fmaf(tv.z, w4r, y1);
            y2 = fmaf(tv.z, w5r, y2); y3 = fmaf(tv.z, w6r, y3);
            y0 = fmaf(tv.w, w4r, y0); y1 = fmaf(tv.w, w5r, y1);
            y2 = fmaf(tv.w, w6r, y2); y3 = fmaf(tv.w, w7r, y3);
            w1r = w5r; w2r = w6r; w3r = w7r;
        }

        // ---- tanh + masked accumulate (registers, no atomics) ----
        const int t_out = base + a;
        if (t_out + 0 >= 0 && t_out + 0 < ol) acc0 += fast_tanh(y0);
        if (t_out + 1 >= 0 && t_out + 1 < ol) acc1 += fast_tanh(y1);
        if (t_out + 2 >= 0 && t_out + 2 < ol) acc2 += fast_tanh(y2);
        if (t_out + 3 >= 0 && t_out + 3 < ol) acc3 += fast_tanh(y3);
    }

    // ---- single coalesced store per output ----
    const int o = ow + a;
    if (o + 3 < Dn) {
        *(float4*)&out[o] = make_float4(acc0, acc1, acc2, acc3);
    } else {
        if (o + 0 < Dn) out[o + 0] = acc0;
        if (o + 1 < Dn) out[o + 1] = acc1;
        if (o + 2 < Dn) out[o + 2] = acc2;
        if (o + 3 < Dn) out[o + 3] = acc3;
    }
}

// ---------------- launcher ----------------
extern "C" void kernel_launch(void* const* d_in, const int* in_sizes, int n_in,
                              void* d_out, int out_size, void* d_ws, size_t ws_size,
                              hipStream_t stream) {
    const float* freq    = (const float*)d_in[0];
    const float* velo    = (const float*)d_in[1];
    const float* w1      = (const float*)d_in[2];
    const float* b1      = (const float*)d_in[3];
    const float* w2      = (const float*)d_in[4];
    const float* b2      = (const float*)d_in[5];
    const float* ws1     = (const float*)d_in[6];
    const float* bs1     = (const float*)d_in[7];
    const float* ws2     = (const float*)d_in[8];
    const float* bs2     = (const float*)d_in[9];
    const float* fir     = (const float*)d_in[10];
    const int*   starts  = (const int*)d_in[11];
    const int*   lengths = (const int*)d_in[12];

    const int N  = in_sizes[0];
    const int Dn = out_size;
    float* out = (float*)d_out;

    float* amps   = (float*)d_ws;
    int*   outlen = (int*)((char*)d_ws + (size_t)N * 8 * sizeof(float));
    float* veln   = (float*)((char*)d_ws + (size_t)N * 8 * sizeof(float) + (size_t)N * sizeof(int));

    params_k<<<(N + 255) / 256, 256, 0, stream>>>(
        freq, velo, w1, b1, w2, b2, ws1, bs1, ws2, bs2,
        starts, lengths, Dn, N, amps, outlen, veln);

    int n_tiles = (Dn + TO - 1) / TO;
    synth_gather_k<<<n_tiles, 256, 0, stream>>>(
        freq, starts, amps, outlen, veln, fir, out, Dn, N);
}

// Round 8
// 216.286 us; speedup vs baseline: 1.3480x; 1.3480x over previous
//
#include <hip/hip_runtime.h>
#include <math.h>

#define LMAX  32768
#define WWIN  1024
#define KFIR  128
#define WOUT  256                // outputs per wave (4 per lane, consecutive)
#define TO    1024               // outputs per block (4 waves)
#define HALO  128
#define SEGW  384                // 256 + 128 staged samples per wave
#define NMAX  1024               // max notes

// ---------------- per-note parameter kernel ----------------
__global__ __launch_bounds__(256) void params_k(
    const float* __restrict__ freq, const float* __restrict__ velo,
    const float* __restrict__ w1,  const float* __restrict__ b1,
    const float* __restrict__ w2,  const float* __restrict__ b2,
    const float* __restrict__ ws1, const float* __restrict__ bs1,
    const float* __restrict__ ws2, const float* __restrict__ bs2,
    const int* __restrict__ starts, const int* __restrict__ lengths,
    int Dn, int N,
    float* __restrict__ amps_out, int* __restrict__ outlen_out,
    float* __restrict__ veln_out)
{
    __shared__ float s_w1[32], s_b1[32], s_w2[64], s_b2[2];
    __shared__ float s_ws1[256], s_bs1[64], s_ws2[512], s_bs2[8];

    const int tid = threadIdx.x;
    if (tid < 32)  { s_w1[tid] = w1[tid]; s_b1[tid] = b1[tid]; }
    if (tid < 64)  { s_w2[tid] = w2[tid]; s_bs1[tid] = bs1[tid]; }
    if (tid < 2)   s_b2[tid] = b2[tid];
    if (tid < 8)   s_bs2[tid] = bs2[tid];
    s_ws1[tid] = ws1[tid];
    s_ws2[tid] = ws2[tid];
    s_ws2[tid + 256] = ws2[tid + 256];
    __syncthreads();

    const int n = blockIdx.x * blockDim.x + tid;
    if (n >= N) return;

    int st  = starts[n];
    int len = lengths[n];
    int ol  = min(st + len, Dn) - st;
    ol = max(0, min(ol, LMAX));
    outlen_out[n] = ol;

    float v = velo[n] * (1.0f / 127.0f);
    veln_out[n] = v;

    float nt = (float)st / (float)Dn;

    float lat0 = s_b2[0], lat1 = s_b2[1];
    #pragma unroll
    for (int j = 0; j < 32; ++j) {
        float h = fmaxf(fmaf(nt, s_w1[j], s_b1[j]), 0.0f);
        lat0 = fmaf(h, s_w2[j * 2 + 0], lat0);
        lat1 = fmaf(h, s_w2[j * 2 + 1], lat1);
    }

    const float f0 = freq[n], f1 = v, f2 = lat0, f3 = lat1;

    float acc[8];
    #pragma unroll
    for (int h = 0; h < 8; ++h) acc[h] = s_bs2[h];
    #pragma unroll
    for (int j = 0; j < 64; ++j) {
        float a = s_bs1[j];
        a = fmaf(f0, s_ws1[0 * 64 + j], a);
        a = fmaf(f1, s_ws1[1 * 64 + j], a);
        a = fmaf(f2, s_ws1[2 * 64 + j], a);
        a = fmaf(f3, s_ws1[3 * 64 + j], a);
        a = fmaxf(a, 0.0f);
        #pragma unroll
        for (int h = 0; h < 8; ++h)
            acc[h] = fmaf(a, s_ws2[j * 8 + h], acc[h]);
    }
    #pragma unroll
    for (int h = 0; h < 8; ++h) {
        float a = acc[h];
        float sp = fmaxf(a, 0.0f) + log1pf(expf(-fabsf(a)));
        amps_out[n * 8 + h] = sp;
    }
}

__device__ __forceinline__ float fast_tanh(float x) {
    float e = __builtin_amdgcn_exp2f(x * 2.8853900817779268f);  // 2*log2(e)
    return fmaf(-2.0f, __builtin_amdgcn_rcpf(e + 1.0f), 1.0f);
}

// one FIR phase: 4 taps (Tq) against window [Fq.y..Fq1.w], shift-free
#define PHASE(Fq, Fq1, Tq)                                                   \
    y0 = fmaf(Tq.x, Fq.y,  y0); y1 = fmaf(Tq.x, Fq.z,  y1);                  \
    y2 = fmaf(Tq.x, Fq.w,  y2); y3 = fmaf(Tq.x, Fq1.x, y3);                  \
    y0 = fmaf(Tq.y, Fq.z,  y0); y1 = fmaf(Tq.y, Fq.w,  y1);                  \
    y2 = fmaf(Tq.y, Fq1.x, y2); y3 = fmaf(Tq.y, Fq1.y, y3);                  \
    y0 = fmaf(Tq.z, Fq.w,  y0); y1 = fmaf(Tq.z, Fq1.x, y1);                  \
    y2 = fmaf(Tq.z, Fq1.y, y2); y3 = fmaf(Tq.z, Fq1.z, y3);                  \
    y0 = fmaf(Tq.w, Fq1.x, y0); y1 = fmaf(Tq.w, Fq1.y, y1);                  \
    y2 = fmaf(Tq.w, Fq1.z, y2); y3 = fmaf(Tq.w, Fq1.w, y3);

// ---------------- gather synthesis kernel ----------------
// grid: ceil(Dn/TO) blocks, 256 threads = 4 independent waves.
// Pipelined FIR: ring of 4 seg-float4 + 4 tap-float4, prefetch distance ~3
// phases (~96 issue cycles) so ds_read latency is covered in-wave.
__global__ __launch_bounds__(256, 4) void synth_gather_k(
    const float* __restrict__ freq_g, const int* __restrict__ starts,
    const float* __restrict__ amps_g, const int* __restrict__ outlen_g,
    const float* __restrict__ veln_g, const float* __restrict__ fir,
    float* __restrict__ out, int Dn, int N)
{
    __shared__ __align__(16) float seg[4][SEGW];
    __shared__ __align__(16) float fir_s[KFIR];
    __shared__ unsigned short note_list[NMAX];
    __shared__ int note_cnt;

    const int tid  = threadIdx.x;
    const int wid  = tid >> 6;
    const int lane = tid & 63;
    const int o0   = blockIdx.x * TO;
    const int o_end = min(o0 + TO, Dn);
    const int ow   = o0 + wid * WOUT;         // this wave's first output

    if (tid < KFIR) fir_s[tid] = fir[tid];
    if (tid == 0) note_cnt = 0;
    __syncthreads();
    for (int j = tid; j < N; j += 256) {
        int st = starts[j];
        int ol = outlen_g[j];
        if (st < o_end && st + ol > o0) {
            int p = atomicAdd(&note_cnt, 1);
            note_list[p] = (unsigned short)j;
        }
    }
    __syncthreads();
    const int K = note_cnt;

    float* __restrict__ segw = seg[wid];
    const int a = lane * 4;                   // wave-local output index / LDS dword base
    float acc0 = 0.f, acc1 = 0.f, acc2 = 0.f, acc3 = 0.f;

    const double inv2pi = 0.15915494309189535;
    const float4* __restrict__ amps4 = (const float4*)amps_g;

    // ---- prefetch pair 0's parameters ----
    int stN = 0, olN = 0; float fN = 0.f, vN = 0.f;
    float4 amN0 = {}, amN1 = {};
    if (K > 0) {
        const int nid = __builtin_amdgcn_readfirstlane((int)note_list[0]);
        stN = starts[nid]; olN = outlen_g[nid];
        fN = freq_g[nid];  vN = veln_g[nid];
        amN0 = amps4[nid * 2]; amN1 = amps4[nid * 2 + 1];
    }

    for (int kk = 0; kk < K; ++kk) {
        const int st = stN, ol = olN;
        const float f = fN, v = vN;
        const float4 am0 = amN0, am1 = amN1;
        if (kk + 1 < K) {
            const int nid = __builtin_amdgcn_readfirstlane((int)note_list[kk + 1]);
            stN = starts[nid]; olN = outlen_g[nid];
            fN = freq_g[nid];  vN = veln_g[nid];
            amN0 = amps4[nid * 2]; amN1 = amps4[nid * 2 + 1];
        }

        const int base = ow - st;             // note-local index of wave's first output
        if (base >= ol || base + WOUT <= 0) continue;   // wave-uniform skip

        const float A0 = am0.x, A1 = am0.y, A2 = am0.z, A3 = am0.w;
        const float A4 = am1.x, A5 = am1.y, A6 = am1.z, A7 = am1.w;
        const double fd = (double)f;

        const int tseed = base - HALO + lane;
        double rev0 = fd * (double)tseed * inv2pi;
        float r0 = (float)(rev0 - floor(rev0));
        float s = __builtin_amdgcn_sinf(r0);
        float c = __builtin_amdgcn_cosf(r0);
        double d64 = fd * 64.0 * inv2pi;
        float r64 = (float)(d64 - floor(d64));
        const float sd = __builtin_amdgcn_sinf(r64);
        const float cd = __builtin_amdgcn_cosf(r64);
        const int wbase = ol - WWIN;

        // ---- stage SEGW samples (same-wave write->read, no barrier) ----
        #pragma unroll
        for (int i = 0; i < 6; ++i) {
            int t = tseed + 64 * i;
            float val = 0.0f;
            if (t >= 0 && t < ol) {
                float tc = c + c;
                float sA = s;
                float sum = A0 * sA;
                float sB = tc * sA;              sum = fmaf(A1, sB, sum);
                float sC = fmaf(tc, sB, -sA);    sum = fmaf(A2, sC, sum);
                float sD = fmaf(tc, sC, -sB);    sum = fmaf(A3, sD, sum);
                float sE = fmaf(tc, sD, -sC);    sum = fmaf(A4, sE, sum);
                float sF = fmaf(tc, sE, -sD);    sum = fmaf(A5, sF, sum);
                float sG = fmaf(tc, sF, -sE);    sum = fmaf(A6, sG, sum);
                float sH = fmaf(tc, sG, -sF);    sum = fmaf(A7, sH, sum);
                int wpos = t - wbase;
                float factor = 1.0f;
                if (wpos >= 0)
                    factor = 0.5f - 0.5f * __builtin_amdgcn_cosf((float)wpos * (1.0f / WWIN));
                val = v * sum * factor;
            }
            segw[lane + 64 * i] = val;
            float ns = fmaf(s, cd, c * sd);
            float nc = fmaf(c, cd, -(s * sd));
            s = ns; c = nc;
        }

        // ---- 128-tap FIR, pipelined ring (no shift chain) ----
        const int t_out = base + a;
        if (t_out + 3 >= 0 && t_out < ol) {
            // preload pipe: seg units u0..u3, tap groups t0..t3
            float4 F0 = *(const float4*)&segw[a];
            float4 F1 = *(const float4*)&segw[a + 4];
            float4 F2 = *(const float4*)&segw[a + 8];
            float4 F3 = *(const float4*)&segw[a + 12];
            float4 T0 = *(const float4*)&fir_s[0];
            float4 T1 = *(const float4*)&fir_s[4];
            float4 T2 = *(const float4*)&fir_s[8];
            float4 T3 = *(const float4*)&fir_s[12];
            float y0 = 0.f, y1 = 0.f, y2 = 0.f, y3 = 0.f;

            // phases 0..27: consume (F[q],F[q+1],T[q]); prefetch u_{m+4},t_{m+4}
            #pragma unroll
            for (int mb = 0; mb < 7; ++mb) {
                const int m4 = mb * 4;
                {   float4 nF = *(const float4*)&segw[a + 4 * (m4 + 4)];
                    float4 nT = *(const float4*)&fir_s[4 * (m4 + 4)];
                    PHASE(F0, F1, T0); F0 = nF; T0 = nT; }
                {   float4 nF = *(const float4*)&segw[a + 4 * (m4 + 5)];
                    float4 nT = *(const float4*)&fir_s[4 * (m4 + 5)];
                    PHASE(F1, F2, T1); F1 = nF; T1 = nT; }
                {   float4 nF = *(const float4*)&segw[a + 4 * (m4 + 6)];
                    float4 nT = *(const float4*)&fir_s[4 * (m4 + 6)];
                    PHASE(F2, F3, T2); F2 = nF; T2 = nT; }
                {   float4 nF = *(const float4*)&segw[a + 4 * (m4 + 7)];
                    float4 nT = *(const float4*)&fir_s[4 * (m4 + 7)];
                    PHASE(F3, F0, T3); F3 = nF; T3 = nT; }
            }
            // tail phases 28..31 (only u32 remains to load, used in phase 31)
            {   float4 nF = *(const float4*)&segw[a + 128];   // u32
                PHASE(F0, F1, T0); F0 = nF; }
            PHASE(F1, F2, T1);
            PHASE(F2, F3, T2);
            PHASE(F3, F0, T3);

            // ---- tanh + masked accumulate (registers, no atomics) ----
            if (t_out + 0 >= 0 && t_out + 0 < ol) acc0 += fast_tanh(y0);
            if (t_out + 1 >= 0 && t_out + 1 < ol) acc1 += fast_tanh(y1);
            if (t_out + 2 >= 0 && t_out + 2 < ol) acc2 += fast_tanh(y2);
            if (t_out + 3 >= 0 && t_out + 3 < ol) acc3 += fast_tanh(y3);
        }
    }

    // ---- single coalesced store per output ----
    const int o = ow + a;
    if (o + 3 < Dn) {
        *(float4*)&out[o] = make_float4(acc0, acc1, acc2, acc3);
    } else {
        if (o + 0 < Dn) out[o + 0] = acc0;
        if (o + 1 < Dn) out[o + 1] = acc1;
        if (o + 2 < Dn) out[o + 2] = acc2;
        if (o + 3 < Dn) out[o + 3] = acc3;
    }
}

// ---------------- launcher ----------------
extern "C" void kernel_launch(void* const* d_in, const int* in_sizes, int n_in,
                              void* d_out, int out_size, void* d_ws, size_t ws_size,
                              hipStream_t stream) {
    const float* freq    = (const float*)d_in[0];
    const float* velo    = (const float*)d_in[1];
    const float* w1      = (const float*)d_in[2];
    const float* b1      = (const float*)d_in[3];
    const float* w2      = (const float*)d_in[4];
    const float* b2      = (const float*)d_in[5];
    const float* ws1     = (const float*)d_in[6];
    const float* bs1     = (const float*)d_in[7];
    const float* ws2     = (const float*)d_in[8];
    const float* bs2     = (const float*)d_in[9];
    const float* fir     = (const float*)d_in[10];
    const int*   starts  = (const int*)d_in[11];
    const int*   lengths = (const int*)d_in[12];

    const int N  = in_sizes[0];
    const int Dn = out_size;
    float* out = (float*)d_out;

    float* amps   = (float*)d_ws;
    int*   outlen = (int*)((char*)d_ws + (size_t)N * 8 * sizeof(float));
    float* veln   = (float*)((char*)d_ws + (size_t)N * 8 * sizeof(float) + (size_t)N * sizeof(int));

    params_k<<<(N + 255) / 256, 256, 0, stream>>>(
        freq, velo, w1, b1, w2, b2, ws1, bs1, ws2, bs2,
        starts, lengths, Dn, N, amps, outlen, veln);

    int n_tiles = (Dn + TO - 1) / TO;
    synth_gather_k<<<n_tiles, 256, 0, stream>>>(
        freq, starts, amps, outlen, veln, fir, out, Dn, N);
}

// Round 9
// 184.258 us; speedup vs baseline: 1.5823x; 1.1738x over previous
//
#include <hip/hip_runtime.h>
#include <math.h>

#define LMAX  32768
#define WWIN  1024
#define KFIR  128
#define WOUT  256                // outputs per wave (4 per lane, consecutive)
#define TO    1024               // outputs per block (4 waves)
#define HALO  128
#define SEGW  384                // 256 + 128 staged samples per wave
#define NMAX  1024               // max notes

// ---------------- per-note parameter kernel ----------------
__global__ __launch_bounds__(256) void params_k(
    const float* __restrict__ freq, const float* __restrict__ velo,
    const float* __restrict__ w1,  const float* __restrict__ b1,
    const float* __restrict__ w2,  const float* __restrict__ b2,
    const float* __restrict__ ws1, const float* __restrict__ bs1,
    const float* __restrict__ ws2, const float* __restrict__ bs2,
    const int* __restrict__ starts, const int* __restrict__ lengths,
    int Dn, int N,
    float* __restrict__ amps_out, int* __restrict__ outlen_out,
    float* __restrict__ veln_out)
{
    __shared__ float s_w1[32], s_b1[32], s_w2[64], s_b2[2];
    __shared__ float s_ws1[256], s_bs1[64], s_ws2[512], s_bs2[8];

    const int tid = threadIdx.x;
    if (tid < 32)  { s_w1[tid] = w1[tid]; s_b1[tid] = b1[tid]; }
    if (tid < 64)  { s_w2[tid] = w2[tid]; s_bs1[tid] = bs1[tid]; }
    if (tid < 2)   s_b2[tid] = b2[tid];
    if (tid < 8)   s_bs2[tid] = bs2[tid];
    s_ws1[tid] = ws1[tid];
    s_ws2[tid] = ws2[tid];
    s_ws2[tid + 256] = ws2[tid + 256];
    __syncthreads();

    const int n = blockIdx.x * blockDim.x + tid;
    if (n >= N) return;

    int st  = starts[n];
    int len = lengths[n];
    int ol  = min(st + len, Dn) - st;
    ol = max(0, min(ol, LMAX));
    outlen_out[n] = ol;

    float v = velo[n] * (1.0f / 127.0f);
    veln_out[n] = v;

    float nt = (float)st / (float)Dn;

    float lat0 = s_b2[0], lat1 = s_b2[1];
    #pragma unroll
    for (int j = 0; j < 32; ++j) {
        float h = fmaxf(fmaf(nt, s_w1[j], s_b1[j]), 0.0f);
        lat0 = fmaf(h, s_w2[j * 2 + 0], lat0);
        lat1 = fmaf(h, s_w2[j * 2 + 1], lat1);
    }

    const float f0 = freq[n], f1 = v, f2 = lat0, f3 = lat1;

    float acc[8];
    #pragma unroll
    for (int h = 0; h < 8; ++h) acc[h] = s_bs2[h];
    #pragma unroll
    for (int j = 0; j < 64; ++j) {
        float a = s_bs1[j];
        a = fmaf(f0, s_ws1[0 * 64 + j], a);
        a = fmaf(f1, s_ws1[1 * 64 + j], a);
        a = fmaf(f2, s_ws1[2 * 64 + j], a);
        a = fmaf(f3, s_ws1[3 * 64 + j], a);
        a = fmaxf(a, 0.0f);
        #pragma unroll
        for (int h = 0; h < 8; ++h)
            acc[h] = fmaf(a, s_ws2[j * 8 + h], acc[h]);
    }
    #pragma unroll
    for (int h = 0; h < 8; ++h) {
        float a = acc[h];
        float sp = fmaxf(a, 0.0f) + log1pf(expf(-fabsf(a)));
        amps_out[n * 8 + h] = sp;
    }
}

__device__ __forceinline__ float fast_tanh(float x) {
    float e = __builtin_amdgcn_exp2f(x * 2.8853900817779268f);  // 2*log2(e)
    return fmaf(-2.0f, __builtin_amdgcn_rcpf(e + 1.0f), 1.0f);
}

// one FIR phase: 4 taps (Tq) against window [Fq.y..Fq1.w], shift-free
#define PHASE(Fq, Fq1, Tq)                                                   \
    y0 = fmaf(Tq.x, Fq.y,  y0); y1 = fmaf(Tq.x, Fq.z,  y1);                  \
    y2 = fmaf(Tq.x, Fq.w,  y2); y3 = fmaf(Tq.x, Fq1.x, y3);                  \
    y0 = fmaf(Tq.y, Fq.z,  y0); y1 = fmaf(Tq.y, Fq.w,  y1);                  \
    y2 = fmaf(Tq.y, Fq1.x, y2); y3 = fmaf(Tq.y, Fq1.y, y3);                  \
    y0 = fmaf(Tq.z, Fq.w,  y0); y1 = fmaf(Tq.z, Fq1.x, y1);                  \
    y2 = fmaf(Tq.z, Fq1.y, y2); y3 = fmaf(Tq.z, Fq1.z, y3);                  \
    y0 = fmaf(Tq.w, Fq1.x, y0); y1 = fmaf(Tq.w, Fq1.y, y1);                  \
    y2 = fmaf(Tq.w, Fq1.z, y2); y3 = fmaf(Tq.w, Fq1.w, y3);

// ---------------- gather synthesis kernel ----------------
// grid: ceil(Dn/TO) blocks, 256 threads = 4 independent waves.
// Pipelined FIR: ring of 4 seg-float4 + 4 tap-float4, prefetch distance ~3
// phases so ds_read latency is covered in-wave.
// __launch_bounds__(256,3): ~170-VGPR cap keeps the full ring + prefetch
// state in registers (64-cap caused ~49 MB/dispatch scratch spill in r8);
// measured wave supply (~2/SIMD avg) never exceeded 3/SIMD anyway.
__global__ __launch_bounds__(256, 3) void synth_gather_k(
    const float* __restrict__ freq_g, const int* __restrict__ starts,
    const float* __restrict__ amps_g, const int* __restrict__ outlen_g,
    const float* __restrict__ veln_g, const float* __restrict__ fir,
    float* __restrict__ out, int Dn, int N)
{
    __shared__ __align__(16) float seg[4][SEGW];
    __shared__ __align__(16) float fir_s[KFIR];
    __shared__ unsigned short note_list[NMAX];
    __shared__ int note_cnt;

    const int tid  = threadIdx.x;
    const int wid  = tid >> 6;
    const int lane = tid & 63;
    const int o0   = blockIdx.x * TO;
    const int o_end = min(o0 + TO, Dn);
    const int ow   = o0 + wid * WOUT;         // this wave's first output

    if (tid < KFIR) fir_s[tid] = fir[tid];
    if (tid == 0) note_cnt = 0;
    __syncthreads();
    for (int j = tid; j < N; j += 256) {
        int st = starts[j];
        int ol = outlen_g[j];
        if (st < o_end && st + ol > o0) {
            int p = atomicAdd(&note_cnt, 1);
            note_list[p] = (unsigned short)j;
        }
    }
    __syncthreads();
    const int K = note_cnt;

    float* __restrict__ segw = seg[wid];
    const int a = lane * 4;                   // wave-local output index / LDS dword base
    float acc0 = 0.f, acc1 = 0.f, acc2 = 0.f, acc3 = 0.f;

    const double inv2pi = 0.15915494309189535;
    const float4* __restrict__ amps4 = (const float4*)amps_g;

    // ---- prefetch pair 0's parameters ----
    int stN = 0, olN = 0; float fN = 0.f, vN = 0.f;
    float4 amN0 = {}, amN1 = {};
    if (K > 0) {
        const int nid = __builtin_amdgcn_readfirstlane((int)note_list[0]);
        stN = starts[nid]; olN = outlen_g[nid];
        fN = freq_g[nid];  vN = veln_g[nid];
        amN0 = amps4[nid * 2]; amN1 = amps4[nid * 2 + 1];
    }

    for (int kk = 0; kk < K; ++kk) {
        const int st = stN, ol = olN;
        const float f = fN, v = vN;
        const float4 am0 = amN0, am1 = amN1;
        if (kk + 1 < K) {
            const int nid = __builtin_amdgcn_readfirstlane((int)note_list[kk + 1]);
            stN = starts[nid]; olN = outlen_g[nid];
            fN = freq_g[nid];  vN = veln_g[nid];
            amN0 = amps4[nid * 2]; amN1 = amps4[nid * 2 + 1];
        }

        const int base = ow - st;             // note-local index of wave's first output
        if (base >= ol || base + WOUT <= 0) continue;   // wave-uniform skip

        const float A0 = am0.x, A1 = am0.y, A2 = am0.z, A3 = am0.w;
        const float A4 = am1.x, A5 = am1.y, A6 = am1.z, A7 = am1.w;
        const double fd = (double)f;

        const int tseed = base - HALO + lane;
        double rev0 = fd * (double)tseed * inv2pi;
        float r0 = (float)(rev0 - floor(rev0));
        float s = __builtin_amdgcn_sinf(r0);
        float c = __builtin_amdgcn_cosf(r0);
        double d64 = fd * 64.0 * inv2pi;
        float r64 = (float)(d64 - floor(d64));
        const float sd = __builtin_amdgcn_sinf(r64);
        const float cd = __builtin_amdgcn_cosf(r64);
        const int wbase = ol - WWIN;

        // ---- stage SEGW samples (same-wave write->read, no barrier) ----
        #pragma unroll
        for (int i = 0; i < 6; ++i) {
            int t = tseed + 64 * i;
            float val = 0.0f;
            if (t >= 0 && t < ol) {
                float tc = c + c;
                float sA = s;
                float sum = A0 * sA;
                float sB = tc * sA;              sum = fmaf(A1, sB, sum);
                float sC = fmaf(tc, sB, -sA);    sum = fmaf(A2, sC, sum);
                float sD = fmaf(tc, sC, -sB);    sum = fmaf(A3, sD, sum);
                float sE = fmaf(tc, sD, -sC);    sum = fmaf(A4, sE, sum);
                float sF = fmaf(tc, sE, -sD);    sum = fmaf(A5, sF, sum);
                float sG = fmaf(tc, sF, -sE);    sum = fmaf(A6, sG, sum);
                float sH = fmaf(tc, sG, -sF);    sum = fmaf(A7, sH, sum);
                int wpos = t - wbase;
                float factor = 1.0f;
                if (wpos >= 0)
                    factor = 0.5f - 0.5f * __builtin_amdgcn_cosf((float)wpos * (1.0f / WWIN));
                val = v * sum * factor;
            }
            segw[lane + 64 * i] = val;
            float ns = fmaf(s, cd, c * sd);
            float nc = fmaf(c, cd, -(s * sd));
            s = ns; c = nc;
        }

        // ---- 128-tap FIR, pipelined ring (no shift chain) ----
        const int t_out = base + a;
        if (t_out + 3 >= 0 && t_out < ol) {
            float4 F0 = *(const float4*)&segw[a];
            float4 F1 = *(const float4*)&segw[a + 4];
            float4 F2 = *(const float4*)&segw[a + 8];
            float4 F3 = *(const float4*)&segw[a + 12];
            float4 T0 = *(const float4*)&fir_s[0];
            float4 T1 = *(const float4*)&fir_s[4];
            float4 T2 = *(const float4*)&fir_s[8];
            float4 T3 = *(const float4*)&fir_s[12];
            float y0 = 0.f, y1 = 0.f, y2 = 0.f, y3 = 0.f;

            #pragma unroll
            for (int mb = 0; mb < 7; ++mb) {
                const int m4 = mb * 4;
                {   float4 nF = *(const float4*)&segw[a + 4 * (m4 + 4)];
                    float4 nT = *(const float4*)&fir_s[4 * (m4 + 4)];
                    PHASE(F0, F1, T0); F0 = nF; T0 = nT; }
                {   float4 nF = *(const float4*)&segw[a + 4 * (m4 + 5)];
                    float4 nT = *(const float4*)&fir_s[4 * (m4 + 5)];
                    PHASE(F1, F2, T1); F1 = nF; T1 = nT; }
                {   float4 nF = *(const float4*)&segw[a + 4 * (m4 + 6)];
                    float4 nT = *(const float4*)&fir_s[4 * (m4 + 6)];
                    PHASE(F2, F3, T2); F2 = nF; T2 = nT; }
                {   float4 nF = *(const float4*)&segw[a + 4 * (m4 + 7)];
                    float4 nT = *(const float4*)&fir_s[4 * (m4 + 7)];
                    PHASE(F3, F0, T3); F3 = nF; T3 = nT; }
            }
            {   float4 nF = *(const float4*)&segw[a + 128];   // u32
                PHASE(F0, F1, T0); F0 = nF; }
            PHASE(F1, F2, T1);
            PHASE(F2, F3, T2);
            PHASE(F3, F0, T3);

            if (t_out + 0 >= 0 && t_out + 0 < ol) acc0 += fast_tanh(y0);
            if (t_out + 1 >= 0 && t_out + 1 < ol) acc1 += fast_tanh(y1);
            if (t_out + 2 >= 0 && t_out + 2 < ol) acc2 += fast_tanh(y2);
            if (t_out + 3 >= 0 && t_out + 3 < ol) acc3 += fast_tanh(y3);
        }
    }

    // ---- single coalesced store per output ----
    const int o = ow + a;
    if (o + 3 < Dn) {
        *(float4*)&out[o] = make_float4(acc0, acc1, acc2, acc3);
    } else {
        if (o + 0 < Dn) out[o + 0] = acc0;
        if (o + 1 < Dn) out[o + 1] = acc1;
        if (o + 2 < Dn) out[o + 2] = acc2;
        if (o + 3 < Dn) out[o + 3] = acc3;
    }
}

// ---------------- launcher ----------------
extern "C" void kernel_launch(void* const* d_in, const int* in_sizes, int n_in,
                              void* d_out, int out_size, void* d_ws, size_t ws_size,
                              hipStream_t stream) {
    const float* freq    = (const float*)d_in[0];
    const float* velo    = (const float*)d_in[1];
    const float* w1      = (const float*)d_in[2];
    const float* b1      = (const float*)d_in[3];
    const float* w2      = (const float*)d_in[4];
    const float* b2      = (const float*)d_in[5];
    const float* ws1     = (const float*)d_in[6];
    const float* bs1     = (const float*)d_in[7];
    const float* ws2     = (const float*)d_in[8];
    const float* bs2     = (const float*)d_in[9];
    const float* fir     = (const float*)d_in[10];
    const int*   starts  = (const int*)d_in[11];
    const int*   lengths = (const int*)d_in[12];

    const int N  = in_sizes[0];
    const int Dn = out_size;
    float* out = (float*)d_out;

    float* amps   = (float*)d_ws;
    int*   outlen = (int*)((char*)d_ws + (size_t)N * 8 * sizeof(float));
    float* veln   = (float*)((char*)d_ws + (size_t)N * 8 * sizeof(float) + (size_t)N * sizeof(int));

    params_k<<<(N + 255) / 256, 256, 0, stream>>>(
        freq, velo, w1, b1, w2, b2, ws1, bs1, ws2, bs2,
        starts, lengths, Dn, N, amps, outlen, veln);

    int n_tiles = (Dn + TO - 1) / TO;
    synth_gather_k<<<n_tiles, 256, 0, stream>>>(
        freq, starts, amps, outlen, veln, fir, out, Dn, N);
}

// Round 10
// 159.564 us; speedup vs baseline: 1.8272x; 1.1548x over previous
//
#include <hip/hip_runtime.h>
#include <math.h>

#define LMAX  32768
#define WWIN  1024
#define KFIR  128
#define WOUT  256                // outputs per wave
#define TO    1024               // outputs per block (4 waves)
#define SEGX  384                // staged samples per wave: t in [base-127, base+257)
#define CPAD  400                // padded shift-copy length (zero tail for zero-A region)
#define NMAX  1024               // max notes

typedef _Float16 v8h __attribute__((ext_vector_type(8)));
typedef float    v4f __attribute__((ext_vector_type(4)));

// ---------------- per-note parameter kernel ----------------
__global__ __launch_bounds__(256) void params_k(
    const float* __restrict__ freq, const float* __restrict__ velo,
    const float* __restrict__ w1,  const float* __restrict__ b1,
    const float* __restrict__ w2,  const float* __restrict__ b2,
    const float* __restrict__ ws1, const float* __restrict__ bs1,
    const float* __restrict__ ws2, const float* __restrict__ bs2,
    const int* __restrict__ starts, const int* __restrict__ lengths,
    int Dn, int N,
    float* __restrict__ amps_out, int* __restrict__ outlen_out,
    float* __restrict__ veln_out)
{
    __shared__ float s_w1[32], s_b1[32], s_w2[64], s_b2[2];
    __shared__ float s_ws1[256], s_bs1[64], s_ws2[512], s_bs2[8];

    const int tid = threadIdx.x;
    if (tid < 32)  { s_w1[tid] = w1[tid]; s_b1[tid] = b1[tid]; }
    if (tid < 64)  { s_w2[tid] = w2[tid]; s_bs1[tid] = bs1[tid]; }
    if (tid < 2)   s_b2[tid] = b2[tid];
    if (tid < 8)   s_bs2[tid] = bs2[tid];
    s_ws1[tid] = ws1[tid];
    s_ws2[tid] = ws2[tid];
    s_ws2[tid + 256] = ws2[tid + 256];
    __syncthreads();

    const int n = blockIdx.x * blockDim.x + tid;
    if (n >= N) return;

    int st  = starts[n];
    int len = lengths[n];
    int ol  = min(st + len, Dn) - st;
    ol = max(0, min(ol, LMAX));
    outlen_out[n] = ol;

    float v = velo[n] * (1.0f / 127.0f);
    veln_out[n] = v;

    float nt = (float)st / (float)Dn;

    float lat0 = s_b2[0], lat1 = s_b2[1];
    #pragma unroll
    for (int j = 0; j < 32; ++j) {
        float h = fmaxf(fmaf(nt, s_w1[j], s_b1[j]), 0.0f);
        lat0 = fmaf(h, s_w2[j * 2 + 0], lat0);
        lat1 = fmaf(h, s_w2[j * 2 + 1], lat1);
    }

    const float f0 = freq[n], f1 = v, f2 = lat0, f3 = lat1;

    float acc[8];
    #pragma unroll
    for (int h = 0; h < 8; ++h) acc[h] = s_bs2[h];
    #pragma unroll
    for (int j = 0; j < 64; ++j) {
        float a = s_bs1[j];
        a = fmaf(f0, s_ws1[0 * 64 + j], a);
        a = fmaf(f1, s_ws1[1 * 64 + j], a);
        a = fmaf(f2, s_ws1[2 * 64 + j], a);
        a = fmaf(f3, s_ws1[3 * 64 + j], a);
        a = fmaxf(a, 0.0f);
        #pragma unroll
        for (int h = 0; h < 8; ++h)
            acc[h] = fmaf(a, s_ws2[j * 8 + h], acc[h]);
    }
    #pragma unroll
    for (int h = 0; h < 8; ++h) {
        float a = acc[h];
        float sp = fmaxf(a, 0.0f) + log1pf(expf(-fabsf(a)));
        amps_out[n * 8 + h] = sp;
    }
}

__device__ __forceinline__ float fast_tanh(float x) {
    float e = __builtin_amdgcn_exp2f(x * 2.8853900817779268f);  // 2*log2(e)
    return fmaf(-2.0f, __builtin_amdgcn_rcpf(e + 1.0f), 1.0f);
}

// ---------------- gather synthesis kernel (MFMA FIR) ----------------
// Per wave: y[16m+n] = D[m][n], D = A(16x384) x B(384x16) via 12x
// mfma_f32_16x16x32_f16.  A = shifted filter bank A[m][k'] = fir[k'-16m]
// (constant; 12 register fragments).  B[k'][n] = seg2[n+k'] where
// seg2[x] = synthesized sample t = base-127+x (fp16).  B fragments are
// ds_read_b128-aligned via 8 shift-copies: copyS[x] = seg2[x+S], lane reads
// copy[n&7].  Pad [376,400) zeroed once (only read under zero-A, NaN guard).
__global__ __launch_bounds__(256, 3) void synth_gather_k(
    const float* __restrict__ freq_g, const int* __restrict__ starts,
    const float* __restrict__ amps_g, const int* __restrict__ outlen_g,
    const float* __restrict__ veln_g, const float* __restrict__ fir,
    float* __restrict__ out, int Dn, int N)
{
    __shared__ __align__(16) _Float16 segc[4][8][CPAD];   // 25.6 KB
    __shared__ float fir_s[KFIR];
    __shared__ unsigned short note_list[NMAX];
    __shared__ int note_cnt;

    const int tid  = threadIdx.x;
    const int wid  = tid >> 6;
    const int lane = tid & 63;
    const int m    = lane & 15;
    const int quad = lane >> 4;
    const int o0   = blockIdx.x * TO;
    const int o_end = min(o0 + TO, Dn);
    const int ow   = o0 + wid * WOUT;         // this wave's first output

    if (tid < KFIR) fir_s[tid] = fir[tid];
    if (tid == 0) note_cnt = 0;
    __syncthreads();
    for (int j = tid; j < N; j += 256) {
        int st = starts[j];
        int ol = outlen_g[j];
        if (st < o_end && st + ol > o0) {
            int p = atomicAdd(&note_cnt, 1);
            note_list[p] = (unsigned short)j;
        }
    }
    __syncthreads();
    const int K = note_cnt;

    // ---- A fragments: shifted filter bank (constant for whole kernel) ----
    v8h afrag[12];
    #pragma unroll
    for (int t = 0; t < 12; ++t) {
        v8h af;
        #pragma unroll
        for (int j = 0; j < 8; ++j) {
            int idx = 32 * t + 8 * quad + j - 16 * m;
            float fv = (idx >= 0 && idx < KFIR) ? fir_s[idx] : 0.0f;
            af[j] = (_Float16)fv;
        }
        afrag[t] = af;
    }

    // ---- zero pad tails of this wave's shift-copies (read only under zero-A) ----
    for (int z = lane; z < 8 * 24; z += 64) {
        int S = z / 24, off = z % 24;
        segc[wid][S][376 + off] = (_Float16)0.0f;
    }

    // per-lane constant B read base: copy S=m&7, start unit (m&8)+8*quad (16B aligned)
    const _Float16* __restrict__ bbase = &segc[wid][m & 7][(m & 8) + 8 * quad];

    float acc0 = 0.f, acc1 = 0.f, acc2 = 0.f, acc3 = 0.f;

    const double inv2pi = 0.15915494309189535;
    const float4* __restrict__ amps4 = (const float4*)amps_g;

    // ---- prefetch pair 0's parameters ----
    int stN = 0, olN = 0; float fN = 0.f, vN = 0.f;
    float4 amN0 = {}, amN1 = {};
    if (K > 0) {
        const int nid = __builtin_amdgcn_readfirstlane((int)note_list[0]);
        stN = starts[nid]; olN = outlen_g[nid];
        fN = freq_g[nid];  vN = veln_g[nid];
        amN0 = amps4[nid * 2]; amN1 = amps4[nid * 2 + 1];
    }

    for (int kk = 0; kk < K; ++kk) {
        const int st = stN, ol = olN;
        const float f = fN, v = vN;
        const float4 am0 = amN0, am1 = amN1;
        if (kk + 1 < K) {
            const int nid = __builtin_amdgcn_readfirstlane((int)note_list[kk + 1]);
            stN = starts[nid]; olN = outlen_g[nid];
            fN = freq_g[nid];  vN = veln_g[nid];
            amN0 = amps4[nid * 2]; amN1 = amps4[nid * 2 + 1];
        }

        const int base = ow - st;             // note-local index of wave's first output
        if (base >= ol || base + WOUT <= 0) continue;   // wave-uniform skip

        const float A0 = am0.x, A1 = am0.y, A2 = am0.z, A3 = am0.w;
        const float A4 = am1.x, A5 = am1.y, A6 = am1.z, A7 = am1.w;
        const double fd = (double)f;

        // phase seed (f64 once per pair) + fixed-angle rotation stepping
        const int tseed = base - 127 + lane;
        double rev0 = fd * (double)tseed * inv2pi;
        float r0 = (float)(rev0 - floor(rev0));
        float s = __builtin_amdgcn_sinf(r0);
        float c = __builtin_amdgcn_cosf(r0);
        double d64 = fd * 64.0 * inv2pi;
        float r64 = (float)(d64 - floor(d64));
        const float sd = __builtin_amdgcn_sinf(r64);
        const float cd = __builtin_amdgcn_cosf(r64);
        const int wbase = ol - WWIN;

        // ---- stage SEGX fp16 samples into 8 shift-copies (same-wave, no barrier) ----
        #pragma unroll
        for (int i = 0; i < 6; ++i) {
            int t = tseed + 64 * i;
            float val = 0.0f;
            if (t >= 0 && t < ol) {
                float tc = c + c;
                float sA = s;
                float sum = A0 * sA;
                float sB = tc * sA;              sum = fmaf(A1, sB, sum);
                float sC = fmaf(tc, sB, -sA);    sum = fmaf(A2, sC, sum);
                float sD = fmaf(tc, sC, -sB);    sum = fmaf(A3, sD, sum);
                float sE = fmaf(tc, sD, -sC);    sum = fmaf(A4, sE, sum);
                float sF = fmaf(tc, sE, -sD);    sum = fmaf(A5, sF, sum);
                float sG = fmaf(tc, sF, -sE);    sum = fmaf(A6, sG, sum);
                float sH = fmaf(tc, sG, -sF);    sum = fmaf(A7, sH, sum);
                int wpos = t - wbase;
                float factor = 1.0f;
                if (wpos >= 0)
                    factor = 0.5f - 0.5f * __builtin_amdgcn_cosf((float)wpos * (1.0f / WWIN));
                val = v * sum * factor;
            }
            _Float16 h = (_Float16)val;
            const int x = lane + 64 * i;
            if (i == 0) {
                #pragma unroll
                for (int S = 0; S < 8; ++S)
                    if (x >= S) segc[wid][S][x - S] = h;
            } else {
                #pragma unroll
                for (int S = 0; S < 8; ++S)
                    segc[wid][S][x - S] = h;
            }
            float ns = fmaf(s, cd, c * sd);
            float nc = fmaf(c, cd, -(s * sd));
            s = ns; c = nc;
        }

        // ---- FIR as 12x MFMA (2 independent accumulator chains) ----
        v4f C0 = {0.f, 0.f, 0.f, 0.f};
        v4f C1 = {0.f, 0.f, 0.f, 0.f};
        #pragma unroll
        for (int t = 0; t < 6; ++t) {
            v8h bf = *(const v8h*)(bbase + 32 * t);
            C0 = __builtin_amdgcn_mfma_f32_16x16x32_f16(afrag[t], bf, C0, 0, 0, 0);
        }
        #pragma unroll
        for (int t = 6; t < 12; ++t) {
            v8h bf = *(const v8h*)(bbase + 32 * t);
            C1 = __builtin_amdgcn_mfma_f32_16x16x32_f16(afrag[t], bf, C1, 0, 0, 0);
        }

        // ---- tanh + masked accumulate; lane's outputs p = 64*quad + 16r + m ----
        {
            const int tb = base + 64 * quad + m;
            float y;
            y = C0[0] + C1[0]; if (tb +  0 >= 0 && tb +  0 < ol) acc0 += fast_tanh(y);
            y = C0[1] + C1[1]; if (tb + 16 >= 0 && tb + 16 < ol) acc1 += fast_tanh(y);
            y = C0[2] + C1[2]; if (tb + 32 >= 0 && tb + 32 < ol) acc2 += fast_tanh(y);
            y = C0[3] + C1[3]; if (tb + 48 >= 0 && tb + 48 < ol) acc3 += fast_tanh(y);
        }
    }

    // ---- stores (C/D layout: 16-lane coalesced runs) ----
    const int ob = ow + 64 * quad + m;
    if (ob +  0 < Dn) out[ob +  0] = acc0;
    if (ob + 16 < Dn) out[ob + 16] = acc1;
    if (ob + 32 < Dn) out[ob + 32] = acc2;
    if (ob + 48 < Dn) out[ob + 48] = acc3;
}

// ---------------- launcher ----------------
extern "C" void kernel_launch(void* const* d_in, const int* in_sizes, int n_in,
                              void* d_out, int out_size, void* d_ws, size_t ws_size,
                              hipStream_t stream) {
    const float* freq    = (const float*)d_in[0];
    const float* velo    = (const float*)d_in[1];
    const float* w1      = (const float*)d_in[2];
    const float* b1      = (const float*)d_in[3];
    const float* w2      = (const float*)d_in[4];
    const float* b2      = (const float*)d_in[5];
    const float* ws1     = (const float*)d_in[6];
    const float* bs1     = (const float*)d_in[7];
    const float* ws2     = (const float*)d_in[8];
    const float* bs2     = (const float*)d_in[9];
    const float* fir     = (const float*)d_in[10];
    const int*   starts  = (const int*)d_in[11];
    const int*   lengths = (const int*)d_in[12];

    const int N  = in_sizes[0];
    const int Dn = out_size;
    float* out = (float*)d_out;

    float* amps   = (float*)d_ws;
    int*   outlen = (int*)((char*)d_ws + (size_t)N * 8 * sizeof(float));
    float* veln   = (float*)((char*)d_ws + (size_t)N * 8 * sizeof(float) + (size_t)N * sizeof(int));

    params_k<<<(N + 255) / 256, 256, 0, stream>>>(
        freq, velo, w1, b1, w2, b2, ws1, bs1, ws2, bs2,
        starts, lengths, Dn, N, amps, outlen, veln);

    int n_tiles = (Dn + TO - 1) / TO;
    synth_gather_k<<<n_tiles, 256, 0, stream>>>(
        freq, starts, amps, outlen, veln, fir, out, Dn, N);
}

// Round 11
// 153.945 us; speedup vs baseline: 1.8939x; 1.0365x over previous
//
#include <hip/hip_runtime.h>
#include <math.h>

#define LMAX  32768
#define WWIN  1024
#define KFIR  128
#define WOUT  256                // outputs per wave
#define TO    1024               // outputs per block (4 waves)
#define SEGX  384                // staged samples per wave: t in [base-127, base+257)
#define CPAD  400                // padded shift-copy length (halves); 800 B stride (16B mult)
#define NMAX  1024               // max notes

typedef _Float16 v8h __attribute__((ext_vector_type(8)));
typedef _Float16 v4h __attribute__((ext_vector_type(4)));
typedef float    v4f __attribute__((ext_vector_type(4)));

// ---------------- per-note parameter kernel ----------------
__global__ __launch_bounds__(256) void params_k(
    const float* __restrict__ freq, const float* __restrict__ velo,
    const float* __restrict__ w1,  const float* __restrict__ b1,
    const float* __restrict__ w2,  const float* __restrict__ b2,
    const float* __restrict__ ws1, const float* __restrict__ bs1,
    const float* __restrict__ ws2, const float* __restrict__ bs2,
    const int* __restrict__ starts, const int* __restrict__ lengths,
    int Dn, int N,
    float* __restrict__ amps_out, int* __restrict__ outlen_out,
    float* __restrict__ veln_out)
{
    __shared__ float s_w1[32], s_b1[32], s_w2[64], s_b2[2];
    __shared__ float s_ws1[256], s_bs1[64], s_ws2[512], s_bs2[8];

    const int tid = threadIdx.x;
    if (tid < 32)  { s_w1[tid] = w1[tid]; s_b1[tid] = b1[tid]; }
    if (tid < 64)  { s_w2[tid] = w2[tid]; s_bs1[tid] = bs1[tid]; }
    if (tid < 2)   s_b2[tid] = b2[tid];
    if (tid < 8)   s_bs2[tid] = bs2[tid];
    s_ws1[tid] = ws1[tid];
    s_ws2[tid] = ws2[tid];
    s_ws2[tid + 256] = ws2[tid + 256];
    __syncthreads();

    const int n = blockIdx.x * blockDim.x + tid;
    if (n >= N) return;

    int st  = starts[n];
    int len = lengths[n];
    int ol  = min(st + len, Dn) - st;
    ol = max(0, min(ol, LMAX));
    outlen_out[n] = ol;

    float v = velo[n] * (1.0f / 127.0f);
    veln_out[n] = v;

    float nt = (float)st / (float)Dn;

    float lat0 = s_b2[0], lat1 = s_b2[1];
    #pragma unroll
    for (int j = 0; j < 32; ++j) {
        float h = fmaxf(fmaf(nt, s_w1[j], s_b1[j]), 0.0f);
        lat0 = fmaf(h, s_w2[j * 2 + 0], lat0);
        lat1 = fmaf(h, s_w2[j * 2 + 1], lat1);
    }

    const float f0 = freq[n], f1 = v, f2 = lat0, f3 = lat1;

    float acc[8];
    #pragma unroll
    for (int h = 0; h < 8; ++h) acc[h] = s_bs2[h];
    #pragma unroll
    for (int j = 0; j < 64; ++j) {
        float a = s_bs1[j];
        a = fmaf(f0, s_ws1[0 * 64 + j], a);
        a = fmaf(f1, s_ws1[1 * 64 + j], a);
        a = fmaf(f2, s_ws1[2 * 64 + j], a);
        a = fmaf(f3, s_ws1[3 * 64 + j], a);
        a = fmaxf(a, 0.0f);
        #pragma unroll
        for (int h = 0; h < 8; ++h)
            acc[h] = fmaf(a, s_ws2[j * 8 + h], acc[h]);
    }
    #pragma unroll
    for (int h = 0; h < 8; ++h) {
        float a = acc[h];
        float sp = fmaxf(a, 0.0f) + log1pf(expf(-fabsf(a)));
        amps_out[n * 8 + h] = sp;
    }
}

__device__ __forceinline__ float fast_tanh(float x) {
    float e = __builtin_amdgcn_exp2f(x * 2.8853900817779268f);  // 2*log2(e)
    return fmaf(-2.0f, __builtin_amdgcn_rcpf(e + 1.0f), 1.0f);
}

// ---------------- gather synthesis kernel (MFMA FIR, 4 shift-copies) ----------------
// Per wave: y[16m+n] = D[m][n], D = A(16x384) x B(384x16) via 12x
// mfma_f32_16x16x32_f16.  A = shifted filter bank A[m][k'] = fir[k'-16m].
// B[k'][n] = seg2[n+k'], seg2[x] = sample t = base-127+x (fp16).
// B fragment logical start = m + 8q + 32t (misaligned by m&7 halves).
// Copies at shifts c=0..3 (c = m&3): in-copy position (m&~3)+8q+32t is
// 8-byte aligned -> two adjacent v4h loads (LLVM merges to ds_read2_b64).
// Staging writes: 4 per sample (was 8 with the 16B-aligned 8-copy scheme).
__global__ __launch_bounds__(256, 3) void synth_gather_k(
    const float* __restrict__ freq_g, const int* __restrict__ starts,
    const float* __restrict__ amps_g, const int* __restrict__ outlen_g,
    const float* __restrict__ veln_g, const float* __restrict__ fir,
    float* __restrict__ out, int Dn, int N)
{
    __shared__ __align__(16) _Float16 segc[4][4][CPAD];   // 12.8 KB
    __shared__ float fir_s[KFIR];
    __shared__ unsigned short note_list[NMAX];
    __shared__ int note_cnt;

    const int tid  = threadIdx.x;
    const int wid  = tid >> 6;
    const int lane = tid & 63;
    const int m    = lane & 15;
    const int quad = lane >> 4;
    const int o0   = blockIdx.x * TO;
    const int o_end = min(o0 + TO, Dn);
    const int ow   = o0 + wid * WOUT;         // this wave's first output

    if (tid < KFIR) fir_s[tid] = fir[tid];
    if (tid == 0) note_cnt = 0;
    __syncthreads();
    for (int j = tid; j < N; j += 256) {
        int st = starts[j];
        int ol = outlen_g[j];
        if (st < o_end && st + ol > o0) {
            int p = atomicAdd(&note_cnt, 1);
            note_list[p] = (unsigned short)j;
        }
    }
    __syncthreads();
    const int K = note_cnt;

    // ---- A fragments: shifted filter bank (constant for whole kernel) ----
    v8h afrag[12];
    #pragma unroll
    for (int t = 0; t < 12; ++t) {
        v8h af;
        #pragma unroll
        for (int j = 0; j < 8; ++j) {
            int idx = 32 * t + 8 * quad + j - 16 * m;
            float fv = (idx >= 0 && idx < KFIR) ? fir_s[idx] : 0.0f;
            af[j] = (_Float16)fv;
        }
        afrag[t] = af;
    }

    // ---- zero pad tails of this wave's shift-copies (defensive; trivial cost) ----
    for (int z = lane; z < 4 * 24; z += 64) {
        int S = z / 24, off = z % 24;
        segc[wid][S][376 + off] = (_Float16)0.0f;
    }

    // per-lane B read base: copy c = m&3, in-copy half index (m&~3)+8*quad (8B aligned)
    const _Float16* __restrict__ bbase = &segc[wid][m & 3][(m & ~3) + 8 * quad];

    float acc0 = 0.f, acc1 = 0.f, acc2 = 0.f, acc3 = 0.f;

    const double inv2pi = 0.15915494309189535;
    const float4* __restrict__ amps4 = (const float4*)amps_g;

    // ---- prefetch pair 0's parameters ----
    int stN = 0, olN = 0; float fN = 0.f, vN = 0.f;
    float4 amN0 = {}, amN1 = {};
    if (K > 0) {
        const int nid = __builtin_amdgcn_readfirstlane((int)note_list[0]);
        stN = starts[nid]; olN = outlen_g[nid];
        fN = freq_g[nid];  vN = veln_g[nid];
        amN0 = amps4[nid * 2]; amN1 = amps4[nid * 2 + 1];
    }

    for (int kk = 0; kk < K; ++kk) {
        const int st = stN, ol = olN;
        const float f = fN, v = vN;
        const float4 am0 = amN0, am1 = amN1;
        if (kk + 1 < K) {
            const int nid = __builtin_amdgcn_readfirstlane((int)note_list[kk + 1]);
            stN = starts[nid]; olN = outlen_g[nid];
            fN = freq_g[nid];  vN = veln_g[nid];
            amN0 = amps4[nid * 2]; amN1 = amps4[nid * 2 + 1];
        }

        const int base = ow - st;             // note-local index of wave's first output
        if (base >= ol || base + WOUT <= 0) continue;   // wave-uniform skip

        const float A0 = am0.x, A1 = am0.y, A2 = am0.z, A3 = am0.w;
        const float A4 = am1.x, A5 = am1.y, A6 = am1.z, A7 = am1.w;
        const double fd = (double)f;

        // phase seed (f64 once per pair) + fixed-angle rotation stepping
        const int tseed = base - 127 + lane;
        double rev0 = fd * (double)tseed * inv2pi;
        float r0 = (float)(rev0 - floor(rev0));
        float s = __builtin_amdgcn_sinf(r0);
        float c = __builtin_amdgcn_cosf(r0);
        double d64 = fd * 64.0 * inv2pi;
        float r64 = (float)(d64 - floor(d64));
        const float sd = __builtin_amdgcn_sinf(r64);
        const float cd = __builtin_amdgcn_cosf(r64);
        const int wbase = ol - WWIN;

        // ---- stage SEGX fp16 samples into 4 shift-copies (same-wave, no barrier) ----
        #pragma unroll
        for (int i = 0; i < 6; ++i) {
            int t = tseed + 64 * i;
            float val = 0.0f;
            if (t >= 0 && t < ol) {
                float tc = c + c;
                float sA = s;
                float sum = A0 * sA;
                float sB = tc * sA;              sum = fmaf(A1, sB, sum);
                float sC = fmaf(tc, sB, -sA);    sum = fmaf(A2, sC, sum);
                float sD = fmaf(tc, sC, -sB);    sum = fmaf(A3, sD, sum);
                float sE = fmaf(tc, sD, -sC);    sum = fmaf(A4, sE, sum);
                float sF = fmaf(tc, sE, -sD);    sum = fmaf(A5, sF, sum);
                float sG = fmaf(tc, sF, -sE);    sum = fmaf(A6, sG, sum);
                float sH = fmaf(tc, sG, -sF);    sum = fmaf(A7, sH, sum);
                int wpos = t - wbase;
                float factor = 1.0f;
                if (wpos >= 0)
                    factor = 0.5f - 0.5f * __builtin_amdgcn_cosf((float)wpos * (1.0f / WWIN));
                val = v * sum * factor;
            }
            _Float16 h = (_Float16)val;
            const int x = lane + 64 * i;
            if (i == 0) {
                #pragma unroll
                for (int S = 0; S < 4; ++S)
                    if (x >= S) segc[wid][S][x - S] = h;
            } else {
                #pragma unroll
                for (int S = 0; S < 4; ++S)
                    segc[wid][S][x - S] = h;
            }
            float ns = fmaf(s, cd, c * sd);
            float nc = fmaf(c, cd, -(s * sd));
            s = ns; c = nc;
        }

        // ---- FIR as 12x MFMA (2 independent accumulator chains) ----
        v4f C0 = {0.f, 0.f, 0.f, 0.f};
        v4f C1 = {0.f, 0.f, 0.f, 0.f};
        #pragma unroll
        for (int t = 0; t < 6; ++t) {
            v4h lo = *(const v4h*)(bbase + 32 * t);        // 8B aligned
            v4h hi = *(const v4h*)(bbase + 32 * t + 4);    // adjacent -> ds_read2_b64
            v8h bf = __builtin_shufflevector(lo, hi, 0, 1, 2, 3, 4, 5, 6, 7);
            C0 = __builtin_amdgcn_mfma_f32_16x16x32_f16(afrag[t], bf, C0, 0, 0, 0);
        }
        #pragma unroll
        for (int t = 6; t < 12; ++t) {
            v4h lo = *(const v4h*)(bbase + 32 * t);
            v4h hi = *(const v4h*)(bbase + 32 * t + 4);
            v8h bf = __builtin_shufflevector(lo, hi, 0, 1, 2, 3, 4, 5, 6, 7);
            C1 = __builtin_amdgcn_mfma_f32_16x16x32_f16(afrag[t], bf, C1, 0, 0, 0);
        }

        // ---- tanh + masked accumulate; lane's outputs p = 64*quad + 16r + m ----
        {
            const int tb = base + 64 * quad + m;
            float y;
            y = C0[0] + C1[0]; if (tb +  0 >= 0 && tb +  0 < ol) acc0 += fast_tanh(y);
            y = C0[1] + C1[1]; if (tb + 16 >= 0 && tb + 16 < ol) acc1 += fast_tanh(y);
            y = C0[2] + C1[2]; if (tb + 32 >= 0 && tb + 32 < ol) acc2 += fast_tanh(y);
            y = C0[3] + C1[3]; if (tb + 48 >= 0 && tb + 48 < ol) acc3 += fast_tanh(y);
        }
    }

    // ---- stores (C/D layout: 16-lane coalesced runs) ----
    const int ob = ow + 64 * quad + m;
    if (ob +  0 < Dn) out[ob +  0] = acc0;
    if (ob + 16 < Dn) out[ob + 16] = acc1;
    if (ob + 32 < Dn) out[ob + 32] = acc2;
    if (ob + 48 < Dn) out[ob + 48] = acc3;
}

// ---------------- launcher ----------------
extern "C" void kernel_launch(void* const* d_in, const int* in_sizes, int n_in,
                              void* d_out, int out_size, void* d_ws, size_t ws_size,
                              hipStream_t stream) {
    const float* freq    = (const float*)d_in[0];
    const float* velo    = (const float*)d_in[1];
    const float* w1      = (const float*)d_in[2];
    const float* b1      = (const float*)d_in[3];
    const float* w2      = (const float*)d_in[4];
    const float* b2      = (const float*)d_in[5];
    const float* ws1     = (const float*)d_in[6];
    const float* bs1     = (const float*)d_in[7];
    const float* ws2     = (const float*)d_in[8];
    const float* bs2     = (const float*)d_in[9];
    const float* fir     = (const float*)d_in[10];
    const int*   starts  = (const int*)d_in[11];
    const int*   lengths = (const int*)d_in[12];

    const int N  = in_sizes[0];
    const int Dn = out_size;
    float* out = (float*)d_out;

    float* amps   = (float*)d_ws;
    int*   outlen = (int*)((char*)d_ws + (size_t)N * 8 * sizeof(float));
    float* veln   = (float*)((char*)d_ws + (size_t)N * 8 * sizeof(float) + (size_t)N * sizeof(int));

    params_k<<<(N + 255) / 256, 256, 0, stream>>>(
        freq, velo, w1, b1, w2, b2, ws1, bs1, ws2, bs2,
        starts, lengths, Dn, N, amps, outlen, veln);

    int n_tiles = (Dn + TO - 1) / TO;
    synth_gather_k<<<n_tiles, 256, 0, stream>>>(
        freq, starts, amps, outlen, veln, fir, out, Dn, N);
}

// Round 12
// 144.049 us; speedup vs baseline: 2.0240x; 1.0687x over previous
//
#include <hip/hip_runtime.h>
#include <math.h>

#define LMAX  32768
#define WWIN  1024
#define KFIR  128
#define WOUT  512                // outputs per wave (two 256-output MFMA chunks)
#define TO    1024               // outputs per block (2 waves)
#define SEGX  640                // staged samples per wave: t in [base-127, base+513)
#define CPAD  656                // padded shift-copy length (halves); 1312 B (16B mult)
#define NMAX  1024               // max notes

typedef _Float16 v8h __attribute__((ext_vector_type(8)));
typedef _Float16 v4h __attribute__((ext_vector_type(4)));
typedef float    v4f __attribute__((ext_vector_type(4)));

// ---------------- per-note parameter kernel ----------------
// amps are pre-multiplied by normalized velocity (exact fold: seg = v*sum ==
// sum with A_h := v*A_h).
__global__ __launch_bounds__(256) void params_k(
    const float* __restrict__ freq, const float* __restrict__ velo,
    const float* __restrict__ w1,  const float* __restrict__ b1,
    const float* __restrict__ w2,  const float* __restrict__ b2,
    const float* __restrict__ ws1, const float* __restrict__ bs1,
    const float* __restrict__ ws2, const float* __restrict__ bs2,
    const int* __restrict__ starts, const int* __restrict__ lengths,
    int Dn, int N,
    float* __restrict__ amps_out, int* __restrict__ outlen_out)
{
    __shared__ float s_w1[32], s_b1[32], s_w2[64], s_b2[2];
    __shared__ float s_ws1[256], s_bs1[64], s_ws2[512], s_bs2[8];

    const int tid = threadIdx.x;
    if (tid < 32)  { s_w1[tid] = w1[tid]; s_b1[tid] = b1[tid]; }
    if (tid < 64)  { s_w2[tid] = w2[tid]; s_bs1[tid] = bs1[tid]; }
    if (tid < 2)   s_b2[tid] = b2[tid];
    if (tid < 8)   s_bs2[tid] = bs2[tid];
    s_ws1[tid] = ws1[tid];
    s_ws2[tid] = ws2[tid];
    s_ws2[tid + 256] = ws2[tid + 256];
    __syncthreads();

    const int n = blockIdx.x * blockDim.x + tid;
    if (n >= N) return;

    int st  = starts[n];
    int len = lengths[n];
    int ol  = min(st + len, Dn) - st;
    ol = max(0, min(ol, LMAX));
    outlen_out[n] = ol;

    float v = velo[n] * (1.0f / 127.0f);
    float nt = (float)st / (float)Dn;

    float lat0 = s_b2[0], lat1 = s_b2[1];
    #pragma unroll
    for (int j = 0; j < 32; ++j) {
        float h = fmaxf(fmaf(nt, s_w1[j], s_b1[j]), 0.0f);
        lat0 = fmaf(h, s_w2[j * 2 + 0], lat0);
        lat1 = fmaf(h, s_w2[j * 2 + 1], lat1);
    }

    const float f0 = freq[n], f1 = v, f2 = lat0, f3 = lat1;

    float acc[8];
    #pragma unroll
    for (int h = 0; h < 8; ++h) acc[h] = s_bs2[h];
    #pragma unroll
    for (int j = 0; j < 64; ++j) {
        float a = s_bs1[j];
        a = fmaf(f0, s_ws1[0 * 64 + j], a);
        a = fmaf(f1, s_ws1[1 * 64 + j], a);
        a = fmaf(f2, s_ws1[2 * 64 + j], a);
        a = fmaf(f3, s_ws1[3 * 64 + j], a);
        a = fmaxf(a, 0.0f);
        #pragma unroll
        for (int h = 0; h < 8; ++h)
            acc[h] = fmaf(a, s_ws2[j * 8 + h], acc[h]);
    }
    #pragma unroll
    for (int h = 0; h < 8; ++h) {
        float a = acc[h];
        float sp = fmaxf(a, 0.0f) + log1pf(expf(-fabsf(a)));
        amps_out[n * 8 + h] = sp * v;            // velocity folded in
    }
}

__device__ __forceinline__ float fast_tanh(float x) {
    float e = __builtin_amdgcn_exp2f(x * 2.8853900817779268f);  // 2*log2(e)
    return fmaf(-2.0f, __builtin_amdgcn_rcpf(e + 1.0f), 1.0f);
}

// ---------------- gather synthesis kernel (MFMA FIR, dual-chunk waves) ----------------
// Per wave: 512 outputs as two 256-output MFMA chunks over one 640-sample
// staging.  y[16m+n] chunkA = D[m][n], D = A(16x384) x B(384x16), 12 MFMA;
// chunkB identical with B offset +256 halves.  A = shifted filter bank
// A[m][k'] = fir[k'-16m] (constant frags).  seg2[x] = sample t=base-127+x
// (fp16), stored in 4 shift-copies (c = m&3) so B reads are 8B-aligned
// (pairs of v4h -> ds_read2_b64).  Copy tails [640-S,656) zeroed once
// (read only under zero-A coefficients; NaN guard).
__global__ __launch_bounds__(128, 3) void synth_gather_k(
    const float* __restrict__ freq_g, const int* __restrict__ starts,
    const float* __restrict__ amps_g, const int* __restrict__ outlen_g,
    const float* __restrict__ fir,
    float* __restrict__ out, int Dn, int N)
{
    __shared__ __align__(16) _Float16 segc[2][4][CPAD];   // 10.5 KB
    __shared__ float fir_s[KFIR];
    __shared__ unsigned short note_list[NMAX];
    __shared__ int note_cnt;

    const int tid  = threadIdx.x;
    const int wid  = tid >> 6;
    const int lane = tid & 63;
    const int m    = lane & 15;
    const int quad = lane >> 4;
    const int o0   = blockIdx.x * TO;
    const int o_end = min(o0 + TO, Dn);
    const int ow   = o0 + wid * WOUT;         // this wave's first output

    fir_s[tid] = fir[tid];                    // 128 threads, 128 taps
    if (tid == 0) note_cnt = 0;
    __syncthreads();
    for (int j = tid; j < N; j += 128) {
        int st = starts[j];
        int ol = outlen_g[j];
        if (st < o_end && st + ol > o0) {
            int p = atomicAdd(&note_cnt, 1);
            note_list[p] = (unsigned short)j;
        }
    }
    __syncthreads();
    const int K = note_cnt;

    // ---- A fragments: shifted filter bank (constant for whole kernel) ----
    v8h afrag[12];
    #pragma unroll
    for (int t = 0; t < 12; ++t) {
        v8h af;
        #pragma unroll
        for (int j = 0; j < 8; ++j) {
            int idx = 32 * t + 8 * quad + j - 16 * m;
            float fv = (idx >= 0 && idx < KFIR) ? fir_s[idx] : 0.0f;
            af[j] = (_Float16)fv;
        }
        afrag[t] = af;
    }

    // ---- zero pad tails [636,656) of this wave's shift-copies ----
    for (int z = lane; z < 4 * 20; z += 64) {
        int S = z / 20, off = z % 20;
        segc[wid][S][636 + off] = (_Float16)0.0f;
    }

    // per-lane B read base: copy c = m&3, in-copy half index (m&~3)+8*quad (8B aligned)
    const _Float16* __restrict__ bbase = &segc[wid][m & 3][(m & ~3) + 8 * quad];

    float accA0 = 0.f, accA1 = 0.f, accA2 = 0.f, accA3 = 0.f;
    float accB0 = 0.f, accB1 = 0.f, accB2 = 0.f, accB3 = 0.f;

    const double inv2pi = 0.15915494309189535;
    const float4* __restrict__ amps4 = (const float4*)amps_g;

    // ---- prefetch pair 0's parameters ----
    int stN = 0, olN = 0; float fN = 0.f;
    float4 amN0 = {}, amN1 = {};
    if (K > 0) {
        const int nid = __builtin_amdgcn_readfirstlane((int)note_list[0]);
        stN = starts[nid]; olN = outlen_g[nid];
        fN = freq_g[nid];
        amN0 = amps4[nid * 2]; amN1 = amps4[nid * 2 + 1];
    }

    for (int kk = 0; kk < K; ++kk) {
        const int st = stN, ol = olN;
        const float f = fN;
        const float4 am0 = amN0, am1 = amN1;
        if (kk + 1 < K) {
            const int nid = __builtin_amdgcn_readfirstlane((int)note_list[kk + 1]);
            stN = starts[nid]; olN = outlen_g[nid];
            fN = freq_g[nid];
            amN0 = amps4[nid * 2]; amN1 = amps4[nid * 2 + 1];
        }

        const int base = ow - st;             // note-local index of wave's first output
        if (base >= ol || base + WOUT <= 0) continue;   // wave-uniform skip

        const float A0 = am0.x, A1 = am0.y, A2 = am0.z, A3 = am0.w;
        const float A4 = am1.x, A5 = am1.y, A6 = am1.z, A7 = am1.w;
        const double fd = (double)f;

        // phase seed (f64 once per pair) + fixed-angle rotation stepping
        const int tseed = base - 127 + lane;
        double rev0 = fd * (double)tseed * inv2pi;
        float r0 = (float)(rev0 - floor(rev0));
        float s = __builtin_amdgcn_sinf(r0);
        float c = __builtin_amdgcn_cosf(r0);
        double d64 = fd * 64.0 * inv2pi;
        float r64 = (float)(d64 - floor(d64));
        const float sd = __builtin_amdgcn_sinf(r64);
        const float cd = __builtin_amdgcn_cosf(r64);
        const int wbase = ol - WWIN;

        // wave-uniform fast path: whole staged range in [0, wbase) -> no
        // bounds checks, no Hann window (~90% of pairs for long notes)
        const bool interior = (base >= 127) && (base + 513 <= wbase);

        if (interior) {
            #pragma unroll
            for (int i = 0; i < 10; ++i) {
                float tc = c + c;
                float sA = s;
                float sum = A0 * sA;
                float sB = tc * sA;              sum = fmaf(A1, sB, sum);
                float sC = fmaf(tc, sB, -sA);    sum = fmaf(A2, sC, sum);
                float sD = fmaf(tc, sC, -sB);    sum = fmaf(A3, sD, sum);
                float sE = fmaf(tc, sD, -sC);    sum = fmaf(A4, sE, sum);
                float sF = fmaf(tc, sE, -sD);    sum = fmaf(A5, sF, sum);
                float sG = fmaf(tc, sF, -sE);    sum = fmaf(A6, sG, sum);
                float sH = fmaf(tc, sG, -sF);    sum = fmaf(A7, sH, sum);
                _Float16 h = (_Float16)sum;
                const int x = lane + 64 * i;
                if (i == 0) {
                    #pragma unroll
                    for (int S = 0; S < 4; ++S)
                        if (x >= S) segc[wid][S][x - S] = h;
                } else {
                    #pragma unroll
                    for (int S = 0; S < 4; ++S)
                        segc[wid][S][x - S] = h;
                }
                float ns = fmaf(s, cd, c * sd);
                float nc = fmaf(c, cd, -(s * sd));
                s = ns; c = nc;
            }
        } else {
            #pragma unroll
            for (int i = 0; i < 10; ++i) {
                int t = tseed + 64 * i;
                float val = 0.0f;
                if (t >= 0 && t < ol) {
                    float tc = c + c;
                    float sA = s;
                    float sum = A0 * sA;
                    float sB = tc * sA;              sum = fmaf(A1, sB, sum);
                    float sC = fmaf(tc, sB, -sA);    sum = fmaf(A2, sC, sum);
                    float sD = fmaf(tc, sC, -sB);    sum = fmaf(A3, sD, sum);
                    float sE = fmaf(tc, sD, -sC);    sum = fmaf(A4, sE, sum);
                    float sF = fmaf(tc, sE, -sD);    sum = fmaf(A5, sF, sum);
                    float sG = fmaf(tc, sF, -sE);    sum = fmaf(A6, sG, sum);
                    float sH = fmaf(tc, sG, -sF);    sum = fmaf(A7, sH, sum);
                    int wpos = t - wbase;
                    float factor = 1.0f;
                    if (wpos >= 0)
                        factor = 0.5f - 0.5f * __builtin_amdgcn_cosf((float)wpos * (1.0f / WWIN));
                    val = sum * factor;
                }
                _Float16 h = (_Float16)val;
                const int x = lane + 64 * i;
                if (i == 0) {
                    #pragma unroll
                    for (int S = 0; S < 4; ++S)
                        if (x >= S) segc[wid][S][x - S] = h;
                } else {
                    #pragma unroll
                    for (int S = 0; S < 4; ++S)
                        segc[wid][S][x - S] = h;
                }
                float ns = fmaf(s, cd, c * sd);
                float nc = fmaf(c, cd, -(s * sd));
                s = ns; c = nc;
            }
        }

        // ---- FIR as 24x MFMA, 4 independent accumulator chains ----
        v4f CA0 = {0.f, 0.f, 0.f, 0.f};
        v4f CA1 = {0.f, 0.f, 0.f, 0.f};
        v4f CB0 = {0.f, 0.f, 0.f, 0.f};
        v4f CB1 = {0.f, 0.f, 0.f, 0.f};
        #pragma unroll
        for (int t = 0; t < 6; ++t) {
            v4h lo = *(const v4h*)(bbase + 32 * t);
            v4h hi = *(const v4h*)(bbase + 32 * t + 4);
            v8h bf = __builtin_shufflevector(lo, hi, 0, 1, 2, 3, 4, 5, 6, 7);
            CA0 = __builtin_amdgcn_mfma_f32_16x16x32_f16(afrag[t], bf, CA0, 0, 0, 0);
            v4h lo2 = *(const v4h*)(bbase + 256 + 32 * t);
            v4h hi2 = *(const v4h*)(bbase + 256 + 32 * t + 4);
            v8h bf2 = __builtin_shufflevector(lo2, hi2, 0, 1, 2, 3, 4, 5, 6, 7);
            CB0 = __builtin_amdgcn_mfma_f32_16x16x32_f16(afrag[t], bf2, CB0, 0, 0, 0);
        }
        #pragma unroll
        for (int t = 6; t < 12; ++t) {
            v4h lo = *(const v4h*)(bbase + 32 * t);
            v4h hi = *(const v4h*)(bbase + 32 * t + 4);
            v8h bf = __builtin_shufflevector(lo, hi, 0, 1, 2, 3, 4, 5, 6, 7);
            CA1 = __builtin_amdgcn_mfma_f32_16x16x32_f16(afrag[t], bf, CA1, 0, 0, 0);
            v4h lo2 = *(const v4h*)(bbase + 256 + 32 * t);
            v4h hi2 = *(const v4h*)(bbase + 256 + 32 * t + 4);
            v8h bf2 = __builtin_shufflevector(lo2, hi2, 0, 1, 2, 3, 4, 5, 6, 7);
            CB1 = __builtin_amdgcn_mfma_f32_16x16x32_f16(afrag[t], bf2, CB1, 0, 0, 0);
        }

        // ---- tanh + masked accumulate; chunkA p = 64q+16r+m, chunkB p+256 ----
        {
            const int tb = base + 64 * quad + m;
            float y;
            y = CA0[0] + CA1[0]; if (tb +   0 >= 0 && tb +   0 < ol) accA0 += fast_tanh(y);
            y = CA0[1] + CA1[1]; if (tb +  16 >= 0 && tb +  16 < ol) accA1 += fast_tanh(y);
            y = CA0[2] + CA1[2]; if (tb +  32 >= 0 && tb +  32 < ol) accA2 += fast_tanh(y);
            y = CA0[3] + CA1[3]; if (tb +  48 >= 0 && tb +  48 < ol) accA3 += fast_tanh(y);
            y = CB0[0] + CB1[0]; if (tb + 256 >= 0 && tb + 256 < ol) accB0 += fast_tanh(y);
            y = CB0[1] + CB1[1]; if (tb + 272 >= 0 && tb + 272 < ol) accB1 += fast_tanh(y);
            y = CB0[2] + CB1[2]; if (tb + 288 >= 0 && tb + 288 < ol) accB2 += fast_tanh(y);
            y = CB0[3] + CB1[3]; if (tb + 304 >= 0 && tb + 304 < ol) accB3 += fast_tanh(y);
        }
    }

    // ---- stores (C/D layout: 16-lane coalesced runs) ----
    const int ob = ow + 64 * quad + m;
    if (ob +   0 < Dn) out[ob +   0] = accA0;
    if (ob +  16 < Dn) out[ob +  16] = accA1;
    if (ob +  32 < Dn) out[ob +  32] = accA2;
    if (ob +  48 < Dn) out[ob +  48] = accA3;
    if (ob + 256 < Dn) out[ob + 256] = accB0;
    if (ob + 272 < Dn) out[ob + 272] = accB1;
    if (ob + 288 < Dn) out[ob + 288] = accB2;
    if (ob + 304 < Dn) out[ob + 304] = accB3;
}

// ---------------- launcher ----------------
extern "C" void kernel_launch(void* const* d_in, const int* in_sizes, int n_in,
                              void* d_out, int out_size, void* d_ws, size_t ws_size,
                              hipStream_t stream) {
    const float* freq    = (const float*)d_in[0];
    const float* velo    = (const float*)d_in[1];
    const float* w1      = (const float*)d_in[2];
    const float* b1      = (const float*)d_in[3];
    const float* w2      = (const float*)d_in[4];
    const float* b2      = (const float*)d_in[5];
    const float* ws1     = (const float*)d_in[6];
    const float* bs1     = (const float*)d_in[7];
    const float* ws2     = (const float*)d_in[8];
    const float* bs2     = (const float*)d_in[9];
    const float* fir     = (const float*)d_in[10];
    const int*   starts  = (const int*)d_in[11];
    const int*   lengths = (const int*)d_in[12];

    const int N  = in_sizes[0];
    const int Dn = out_size;
    float* out = (float*)d_out;

    float* amps   = (float*)d_ws;
    int*   outlen = (int*)((char*)d_ws + (size_t)N * 8 * sizeof(float));

    params_k<<<(N + 255) / 256, 256, 0, stream>>>(
        freq, velo, w1, b1, w2, b2, ws1, bs1, ws2, bs2,
        starts, lengths, Dn, N, amps, outlen);

    int n_tiles = (Dn + TO - 1) / TO;
    synth_gather_k<<<n_tiles, 128, 0, stream>>>(
        freq, starts, amps, outlen, fir, out, Dn, N);
}